// Round 4
// baseline (413.826 us; speedup 1.0000x reference)
//
#include <hip/hip_runtime.h>
#include <hip/hip_bf16.h>

#define NN 8192
#define FIN 128
#define FOUT 64

typedef __attribute__((ext_vector_type(8))) short short8;
typedef __attribute__((ext_vector_type(4))) float floatx4;
typedef __attribute__((ext_vector_type(4))) int intx4;

__device__ __forceinline__ short f2bf_rne(float x) {
  union { float f; unsigned u; } c; c.f = x;
  unsigned r = c.u + 0x7fffu + ((c.u >> 16) & 1u);
  return (short)(r >> 16);
}
__device__ __forceinline__ float bf2f(short b) {
  union { unsigned u; float f; } c; c.u = ((unsigned)(unsigned short)b) << 16;
  return c.f;
}

// Kernel A: h = x @ W^T (fp32), s_src/s_dst, and Hb = bf16 h pre-swizzled into
// MFMA-B-fragment order: Hb[((c*4 + ftile)*64 + quad*16 + fi)*8 + v] = h[c*32+quad*8+v][ftile*16+fi]
__global__ __launch_bounds__(256) void prep_kernel(
    const float* __restrict__ x, const float* __restrict__ W,
    const float* __restrict__ att_w,
    short* __restrict__ Hb, float* __restrict__ s_src, float* __restrict__ s_dst) {
  __shared__ float xs[16 * FIN];  // 8 KB: 16 rows of x
  const int t = threadIdx.x;
  const int bid = blockIdx.x;
#pragma unroll
  for (int i = 0; i < 8; ++i)
    xs[t + i * 256] = x[(size_t)bid * (16 * FIN) + t + i * 256];
  __syncthreads();
  const int w = t >> 6;     // wave handles rows w*4 .. w*4+3
  const int f = t & 63;     // lane == output feature
  const float4* Wf4 = (const float4*)(W + f * FIN);
  const float4* xr0 = (const float4*)(xs + (w * 4 + 0) * FIN);
  const float4* xr1 = (const float4*)(xs + (w * 4 + 1) * FIN);
  const float4* xr2 = (const float4*)(xs + (w * 4 + 2) * FIN);
  const float4* xr3 = (const float4*)(xs + (w * 4 + 3) * FIN);
  float h0 = 0.f, h1 = 0.f, h2 = 0.f, h3 = 0.f;
#pragma unroll
  for (int k = 0; k < FIN / 4; ++k) {
    float4 wv = Wf4[k];
    float4 v0 = xr0[k], v1 = xr1[k], v2 = xr2[k], v3 = xr3[k];
    h0 = fmaf(v0.x, wv.x, h0); h0 = fmaf(v0.y, wv.y, h0);
    h0 = fmaf(v0.z, wv.z, h0); h0 = fmaf(v0.w, wv.w, h0);
    h1 = fmaf(v1.x, wv.x, h1); h1 = fmaf(v1.y, wv.y, h1);
    h1 = fmaf(v1.z, wv.z, h1); h1 = fmaf(v1.w, wv.w, h1);
    h2 = fmaf(v2.x, wv.x, h2); h2 = fmaf(v2.y, wv.y, h2);
    h2 = fmaf(v2.z, wv.z, h2); h2 = fmaf(v2.w, wv.w, h2);
    h3 = fmaf(v3.x, wv.x, h3); h3 = fmaf(v3.y, wv.y, h3);
    h3 = fmaf(v3.z, wv.z, h3); h3 = fmaf(v3.w, wv.w, h3);
  }
  const float asrc = att_w[f];
  const float adst = att_w[FOUT + f];
  float hv[4] = {h0, h1, h2, h3};
#pragma unroll
  for (int g = 0; g < 4; ++g) {
    float v1 = hv[g] * asrc;
    float v2 = hv[g] * adst;
#pragma unroll
    for (int off = 32; off > 0; off >>= 1) {
      v1 += __shfl_xor(v1, off, 64);
      v2 += __shfl_xor(v2, off, 64);
    }
    const int r = bid * 16 + w * 4 + g;
    if (f == 0) { s_src[r] = v1; s_dst[r] = v2; }
    const int c = r >> 5;
    const int quad = (r >> 3) & 3;
    const int vv = r & 7;
    const int tile = f >> 4;
    const int fi = f & 15;
    Hb[(((c * 4 + tile) * 64) + quad * 16 + fi) * 8 + vv] = f2bf_rne(hv[g]);
  }
}

// One fused step: 16 rows x 32 j's. Lane computes 8 p-values (A-fragment:
// A[m=lane&15][k=quad*8+v]) and feeds 4 MFMAs (one per 16-feature tile).
__device__ __forceinline__ void gat_step(
    float ssrc, intx4 a0, intx4 a1, float4 s0, float4 s1,
    short8 b0, short8 b1, short8 b2, short8 b3,
    floatx4& acc0, floatx4& acc1, floatx4& acc2, floatx4& acc3, float& dsum) {
  float sdv[8] = {s0.x, s0.y, s0.z, s0.w, s1.x, s1.y, s1.z, s1.w};
  int av[8] = {a0.x, a0.y, a0.z, a0.w, a1.x, a1.y, a1.z, a1.w};
  short8 afrag;
#pragma unroll
  for (int v = 0; v < 8; ++v) {
    float tt = ssrc + sdv[v];
    float e = fmaxf(tt, 0.f) + 0.01f * fminf(tt, 0.f);  // leaky_relu
    float p = __expf(e);
    p = (av[v] > 0) ? p : 0.f;
    short bb = f2bf_rne(p);
    afrag[v] = bb;
    dsum += bf2f(bb);  // denominator from the bf16-rounded weight: exact normalization
  }
  acc0 = __builtin_amdgcn_mfma_f32_16x16x32_bf16(afrag, b0, acc0, 0, 0, 0);
  acc1 = __builtin_amdgcn_mfma_f32_16x16x32_bf16(afrag, b1, acc1, 0, 0, 0);
  acc2 = __builtin_amdgcn_mfma_f32_16x16x32_bf16(afrag, b2, acc2, 0, 0, 0);
  acc3 = __builtin_amdgcn_mfma_f32_16x16x32_bf16(afrag, b3, acc3, 0, 0, 0);
}

// Block: 16 rows, 8 waves; wave w owns j in [w*1024, (w+1)*1024), 32 steps of 32 j.
// adj (the only HBM stream) is software-pipelined 2 steps ahead; s_dst/Hb
// (L2-resident) stay at depth 1. __launch_bounds__(512,4): VGPR<=128.
__global__ __launch_bounds__(512, 4) void gat_kernel(
    const int* __restrict__ adj, const short8* __restrict__ Hb,
    const float* __restrict__ s_src, const float* __restrict__ s_dst,
    float* __restrict__ out) {
  __shared__ float part[8][16][64];   // 32 KB: per-wave partial numerators
  __shared__ float dpart[8][16];      // per-wave partial denominators
  const int tid = threadIdx.x;
  const int w = tid >> 6;
  const int lane = tid & 63;
  const int m = lane & 15;
  const int quad = lane >> 4;
  const int i0 = blockIdx.x * 16;
  const int row = i0 + m;
  const float ssrc = s_src[row];
  const intx4* adjp = (const intx4*)(adj + (size_t)row * NN + w * 1024 + quad * 8);
  const float4* sp = (const float4*)(s_dst + w * 1024 + quad * 8);
  int hb = w * 8192 + lane;  // short8 index for (chunk=w*32, tile 0)
  floatx4 acc0 = {0.f, 0.f, 0.f, 0.f};
  floatx4 acc1 = acc0, acc2 = acc0, acc3 = acc0;
  float dsum = 0.f;

  // ---- software pipeline prologue ----
  // adj: steps 0 and 1 in flight. s/Hb: step 0.
  intx4 a0c = __builtin_nontemporal_load(adjp + 0);
  intx4 a1c = __builtin_nontemporal_load(adjp + 1);
  intx4 a0n = __builtin_nontemporal_load(adjp + 8);
  intx4 a1n = __builtin_nontemporal_load(adjp + 9);
  float4 s0c = sp[0], s1c = sp[1];
  short8 b0c = Hb[hb], b1c = Hb[hb + 64], b2c = Hb[hb + 128], b3c = Hb[hb + 192];

  // main loop: steps 0..29. Prefetch adj(step+2), s/Hb(step+1). All in-bounds
  // (deepest adj prefetch at step==29 is step 31's data).
  for (int step = 0; step < 30; ++step) {
    intx4 a0f = __builtin_nontemporal_load(adjp + 16);
    intx4 a1f = __builtin_nontemporal_load(adjp + 17);
    float4 s0n = sp[8], s1n = sp[9];
    short8 b0n = Hb[hb + 256], b1n = Hb[hb + 320], b2n = Hb[hb + 384], b3n = Hb[hb + 448];
    gat_step(ssrc, a0c, a1c, s0c, s1c, b0c, b1c, b2c, b3c, acc0, acc1, acc2, acc3, dsum);
    a0c = a0n; a1c = a1n; a0n = a0f; a1n = a1f;
    s0c = s0n; s1c = s1n;
    b0c = b0n; b1c = b1n; b2c = b2n; b3c = b3n;
    adjp += 8; sp += 8; hb += 256;
  }
  // epilogue: step 30 (prefetch s/Hb for 31), then step 31
  {
    float4 s0n = sp[8], s1n = sp[9];
    short8 b0n = Hb[hb + 256], b1n = Hb[hb + 320], b2n = Hb[hb + 384], b3n = Hb[hb + 448];
    gat_step(ssrc, a0c, a1c, s0c, s1c, b0c, b1c, b2c, b3c, acc0, acc1, acc2, acc3, dsum);
    gat_step(ssrc, a0n, a1n, s0n, s1n, b0n, b1n, b2n, b3n, acc0, acc1, acc2, acc3, dsum);
  }

  // reduce denominator over quads (lanes with equal lane&15 cover disjoint k)
  dsum += __shfl_xor(dsum, 16, 64);
  dsum += __shfl_xor(dsum, 32, 64);

  // C/D layout: col = lane&15 (feature within tile), row = quad*4 + reg
  const int col = lane & 15;
#pragma unroll
  for (int rg = 0; rg < 4; ++rg) {
    part[w][quad * 4 + rg][col]      = acc0[rg];
    part[w][quad * 4 + rg][16 + col] = acc1[rg];
    part[w][quad * 4 + rg][32 + col] = acc2[rg];
    part[w][quad * 4 + rg][48 + col] = acc3[rg];
  }
  if (quad == 0) dpart[w][m] = dsum;
  __syncthreads();

  // epilogue: sum 8 wave-partials, normalize, ELU, coalesced store
  for (int idx = tid; idx < 16 * 64; idx += 512) {
    int mr = idx >> 6, fc = idx & 63;
    float num = 0.f, den = 0.f;
#pragma unroll
    for (int ww = 0; ww < 8; ++ww) { num += part[ww][mr][fc]; den += dpart[ww][mr]; }
    float o = num / den;
    o = (o > 0.f) ? o : (__expf(o) - 1.f);
    out[(size_t)(i0 + mr) * FOUT + fc] = o;
  }
}

extern "C" void kernel_launch(void* const* d_in, const int* in_sizes, int n_in,
                              void* d_out, int out_size, void* d_ws, size_t ws_size,
                              hipStream_t stream) {
  const float* x     = (const float*)d_in[0];
  const int*   adj   = (const int*)d_in[1];
  const float* W     = (const float*)d_in[2];
  const float* att_w = (const float*)d_in[3];
  float* out = (float*)d_out;
  char* ws = (char*)d_ws;
  short* Hb = (short*)ws;                                   // 1 MB bf16 swizzled h
  float* s_src = (float*)(ws + (size_t)NN * FOUT * sizeof(short));
  float* s_dst = s_src + NN;
  prep_kernel<<<NN / 16, 256, 0, stream>>>(x, W, att_w, Hb, s_src, s_dst);
  gat_kernel<<<NN / 16, 512, 0, stream>>>(adj, (const short8*)Hb, s_src, s_dst, out);
}

// Round 5
// 376.060 us; speedup vs baseline: 1.1004x; 1.1004x over previous
//
#include <hip/hip_runtime.h>
#include <hip/hip_bf16.h>

#define NN 8192
#define FIN 128
#define FOUT 64
#define JCH 256      // columns per chunk
#define NCH 32       // chunks (NCH*JCH == NN)
#define PSTR 264     // Pbuf row stride in shorts: 256 + 8 pad (2-way-free banks)

typedef __attribute__((ext_vector_type(8))) short short8;
typedef __attribute__((ext_vector_type(4))) short short4v;
typedef __attribute__((ext_vector_type(4))) float floatx4;
typedef __attribute__((ext_vector_type(4))) int intx4;

__device__ __forceinline__ short f2bf_rne(float x) {
  union { float f; unsigned u; } c; c.f = x;
  unsigned r = c.u + 0x7fffu + ((c.u >> 16) & 1u);
  return (short)(r >> 16);
}
__device__ __forceinline__ float bf2f(short b) {
  union { unsigned u; float f; } c; c.u = ((unsigned)(unsigned short)b) << 16;
  return c.f;
}

// Kernel A: h = x @ W^T (fp32), s_src/s_dst, and Hb = bf16 h pre-swizzled into
// MFMA-B-fragment order: Hb[((c*4 + ftile)*64 + quad*16 + fi)*8 + v] = h[c*32+quad*8+v][ftile*16+fi]
__global__ __launch_bounds__(256) void prep_kernel(
    const float* __restrict__ x, const float* __restrict__ W,
    const float* __restrict__ att_w,
    short* __restrict__ Hb, float* __restrict__ s_src, float* __restrict__ s_dst) {
  __shared__ float xs[16 * FIN];  // 8 KB: 16 rows of x
  const int t = threadIdx.x;
  const int bid = blockIdx.x;
#pragma unroll
  for (int i = 0; i < 8; ++i)
    xs[t + i * 256] = x[(size_t)bid * (16 * FIN) + t + i * 256];
  __syncthreads();
  const int w = t >> 6;     // wave handles rows w*4 .. w*4+3
  const int f = t & 63;     // lane == output feature
  const float4* Wf4 = (const float4*)(W + f * FIN);
  const float4* xr0 = (const float4*)(xs + (w * 4 + 0) * FIN);
  const float4* xr1 = (const float4*)(xs + (w * 4 + 1) * FIN);
  const float4* xr2 = (const float4*)(xs + (w * 4 + 2) * FIN);
  const float4* xr3 = (const float4*)(xs + (w * 4 + 3) * FIN);
  float h0 = 0.f, h1 = 0.f, h2 = 0.f, h3 = 0.f;
#pragma unroll
  for (int k = 0; k < FIN / 4; ++k) {
    float4 wv = Wf4[k];
    float4 v0 = xr0[k], v1 = xr1[k], v2 = xr2[k], v3 = xr3[k];
    h0 = fmaf(v0.x, wv.x, h0); h0 = fmaf(v0.y, wv.y, h0);
    h0 = fmaf(v0.z, wv.z, h0); h0 = fmaf(v0.w, wv.w, h0);
    h1 = fmaf(v1.x, wv.x, h1); h1 = fmaf(v1.y, wv.y, h1);
    h1 = fmaf(v1.z, wv.z, h1); h1 = fmaf(v1.w, wv.w, h1);
    h2 = fmaf(v2.x, wv.x, h2); h2 = fmaf(v2.y, wv.y, h2);
    h2 = fmaf(v2.z, wv.z, h2); h2 = fmaf(v2.w, wv.w, h2);
    h3 = fmaf(v3.x, wv.x, h3); h3 = fmaf(v3.y, wv.y, h3);
    h3 = fmaf(v3.z, wv.z, h3); h3 = fmaf(v3.w, wv.w, h3);
  }
  const float asrc = att_w[f];
  const float adst = att_w[FOUT + f];
  float hv[4] = {h0, h1, h2, h3};
#pragma unroll
  for (int g = 0; g < 4; ++g) {
    float v1 = hv[g] * asrc;
    float v2 = hv[g] * adst;
#pragma unroll
    for (int off = 32; off > 0; off >>= 1) {
      v1 += __shfl_xor(v1, off, 64);
      v2 += __shfl_xor(v2, off, 64);
    }
    const int r = bid * 16 + w * 4 + g;
    if (f == 0) { s_src[r] = v1; s_dst[r] = v2; }
    const int c = r >> 5;
    const int quad = (r >> 3) & 3;
    const int vv = r & 7;
    const int tile = f >> 4;
    const int fi = f & 15;
    Hb[(((c * 4 + tile) * 64) + quad * 16 + fi) * 8 + vv] = f2bf_rne(hv[g]);
  }
}

// p for 4 consecutive columns of one row; returns packed bf16, accumulates denominator
__device__ __forceinline__ short4v pcalc(float ssrc, intx4 a, float4 s, float& dsum) {
  float sv[4] = {s.x, s.y, s.z, s.w};
  int av[4] = {a.x, a.y, a.z, a.w};
  short4v r;
#pragma unroll
  for (int v = 0; v < 4; ++v) {
    float tt = ssrc + sv[v];
    float e = fmaxf(tt, 0.f) + 0.01f * fminf(tt, 0.f);  // leaky_relu
    float p = __expf(e);
    p = (av[v] > 0) ? p : 0.f;
    short bb = f2bf_rne(p);
    r[v] = bb;
    dsum += bf2f(bb);  // denominator from bf16-rounded weight: exact normalization
  }
  return r;
}

// gat v2: block = 16 rows, 8 waves. Wave w READS adj LINEARLY for rows 2w,2w+1
// (1 KB contiguous per row per chunk), computes bf16 p into a double-buffered
// LDS tile in A-fragment-friendly layout; consume side MFMAs wave w's k-strip
// (32 j) x 4 feature tiles. Chunk order staggered by blockIdx to spread the
// machine-wide column band across all channels. Hb loads issued before adj so
// fast L2 loads are never queued behind the slow HBM stream (in-order vmcnt).
__global__ __launch_bounds__(512, 4) void gat_kernel(
    const int* __restrict__ adj, const short8* __restrict__ Hb,
    const float* __restrict__ s_src, const float* __restrict__ s_dst,
    float* __restrict__ out) {
  __shared__ short Pbuf[2][16][PSTR];  // 16.5 KB: p-values, double-buffered
  __shared__ float part[8][16][64];    // 32 KB: per-wave partial numerators
  __shared__ float dden[16];           // full row denominators
  const int tid = threadIdx.x;
  const int w = tid >> 6;
  const int lane = tid & 63;
  const int m = lane & 15;
  const int quad = lane >> 4;
  const int bid = blockIdx.x;
  const int i0 = bid * 16;
  const int rA = 2 * w, rB = 2 * w + 1;
  const float ssA = s_src[i0 + rA];
  const float ssB = s_src[i0 + rB];
  const int* adjA = adj + (size_t)(i0 + rA) * NN + lane * 4;
  const int* adjB = adj + (size_t)(i0 + rB) * NN + lane * 4;
  const float* sdp = s_dst + lane * 4;

  floatx4 acc0 = {0.f, 0.f, 0.f, 0.f};
  floatx4 acc1 = acc0, acc2 = acc0, acc3 = acc0;
  float dsA = 0.f, dsB = 0.f;

  // ---- prologue: produce chunk cc(0) into buf0; load regs for chunk cc(1) ----
  int q = bid & (NCH - 1);
  intx4 aA = __builtin_nontemporal_load((const intx4*)(adjA + q * JCH));
  intx4 aB = __builtin_nontemporal_load((const intx4*)(adjB + q * JCH));
  float4 sv = *(const float4*)(sdp + q * JCH);
  *(short4v*)&Pbuf[0][rA][lane * 4] = pcalc(ssA, aA, sv, dsA);
  *(short4v*)&Pbuf[0][rB][lane * 4] = pcalc(ssB, aB, sv, dsB);
  q = (bid + 1) & (NCH - 1);
  aA = __builtin_nontemporal_load((const intx4*)(adjA + q * JCH));
  aB = __builtin_nontemporal_load((const intx4*)(adjB + q * JCH));
  sv = *(const float4*)(sdp + q * JCH);

  for (int c = 0; c < NCH; ++c) {
    __syncthreads();  // buf[c&1] produced; buf[(c+1)&1] free (consumed in c-1)
    const int cc = (c + bid) & (NCH - 1);
    // 1) Hb B-fragments for this chunk's k-strip (L2-resident; issue FIRST)
    const short8* hp = Hb + (size_t)(cc * 8 + w) * 4 * 64 + lane;
    short8 h0 = hp[0], h1 = hp[64], h2 = hp[128], h3 = hp[192];
    // 2) produce chunk c+1 from regs loaded in iter c-1
    if (c + 1 < NCH) {
      short4v pA = pcalc(ssA, aA, sv, dsA);
      short4v pB = pcalc(ssB, aB, sv, dsB);
      *(short4v*)&Pbuf[(c + 1) & 1][rA][lane * 4] = pA;
      *(short4v*)&Pbuf[(c + 1) & 1][rB][lane * 4] = pB;
    }
    // 3) adj/s loads for chunk c+2 (slow HBM stream; newest in queue)
    if (c + 2 < NCH) {
      const int cn = (c + 2 + bid) & (NCH - 1);
      aA = __builtin_nontemporal_load((const intx4*)(adjA + cn * JCH));
      aB = __builtin_nontemporal_load((const intx4*)(adjB + cn * JCH));
      sv = *(const float4*)(sdp + cn * JCH);
    }
    // 4) A-fragment from LDS (written by all waves in iter c-1)
    short8 af = *(const short8*)&Pbuf[c & 1][m][w * 32 + quad * 8];
    // 5) MFMA: waits on Hb (older than adj(c+2) in queue -> no coupling)
    acc0 = __builtin_amdgcn_mfma_f32_16x16x32_bf16(af, h0, acc0, 0, 0, 0);
    acc1 = __builtin_amdgcn_mfma_f32_16x16x32_bf16(af, h1, acc1, 0, 0, 0);
    acc2 = __builtin_amdgcn_mfma_f32_16x16x32_bf16(af, h2, acc2, 0, 0, 0);
    acc3 = __builtin_amdgcn_mfma_f32_16x16x32_bf16(af, h3, acc3, 0, 0, 0);
  }

  // full row denominators: wave w produced ALL of rows 2w,2w+1
#pragma unroll
  for (int off = 1; off < 64; off <<= 1) {
    dsA += __shfl_xor(dsA, off, 64);
    dsB += __shfl_xor(dsB, off, 64);
  }
  if (lane == 0) { dden[rA] = dsA; dden[rB] = dsB; }

  // C/D layout: col = lane&15 (feature within tile), row = quad*4 + reg
  const int col = lane & 15;
#pragma unroll
  for (int rg = 0; rg < 4; ++rg) {
    part[w][quad * 4 + rg][col]      = acc0[rg];
    part[w][quad * 4 + rg][16 + col] = acc1[rg];
    part[w][quad * 4 + rg][32 + col] = acc2[rg];
    part[w][quad * 4 + rg][48 + col] = acc3[rg];
  }
  __syncthreads();

  // epilogue: sum 8 wave-partials (disjoint j), normalize, ELU, coalesced store
  for (int idx = tid; idx < 16 * 64; idx += 512) {
    int mr = idx >> 6, fc = idx & 63;
    float num = 0.f;
#pragma unroll
    for (int ww = 0; ww < 8; ++ww) num += part[ww][mr][fc];
    float o = num / dden[mr];
    o = (o > 0.f) ? o : (__expf(o) - 1.f);
    out[(size_t)(i0 + mr) * FOUT + fc] = o;
  }
}

extern "C" void kernel_launch(void* const* d_in, const int* in_sizes, int n_in,
                              void* d_out, int out_size, void* d_ws, size_t ws_size,
                              hipStream_t stream) {
  const float* x     = (const float*)d_in[0];
  const int*   adj   = (const int*)d_in[1];
  const float* W     = (const float*)d_in[2];
  const float* att_w = (const float*)d_in[3];
  float* out = (float*)d_out;
  char* ws = (char*)d_ws;
  short* Hb = (short*)ws;                                   // 1 MB bf16 swizzled h
  float* s_src = (float*)(ws + (size_t)NN * FOUT * sizeof(short));
  float* s_dst = s_src + NN;
  prep_kernel<<<NN / 16, 256, 0, stream>>>(x, W, att_w, Hb, s_src, s_dst);
  gat_kernel<<<NN / 16, 512, 0, stream>>>(adj, (const short8*)Hb, s_src, s_dst, out);
}